// Round 7
// baseline (230.830 us; speedup 1.0000x reference)
//
#include <hip/hip_runtime.h>

#define Bb 2
#define Nn 256
#define Dd 128
#define Rr 32

typedef unsigned short u16;
typedef unsigned int   u32;
typedef __attribute__((ext_vector_type(8))) short bf16x8;
typedef __attribute__((ext_vector_type(4))) short bf16x4;
typedef __attribute__((ext_vector_type(4))) float f32x4;
typedef __attribute__((ext_vector_type(2))) u32   u32x2;

__device__ __forceinline__ short f2bfs(float f){
  u32 u = __float_as_uint(f);
  u += 0x7FFFu + ((u >> 16) & 1u);   // RNE
  return (short)(u >> 16);
}
__device__ __forceinline__ u16 f2bf(float f){
  u32 u = __float_as_uint(f);
  u += 0x7FFFu + ((u >> 16) & 1u);
  return (u16)(u >> 16);
}

// ---- kernel 1: h_T[b][d][i] = (node_s @ src_w)^T  (fp32) -------------------
__global__ __launch_bounds__(128) void hproj_kernel(
    const float* __restrict__ node_s, const float* __restrict__ src_w,
    float* __restrict__ hT_out){
  __shared__ float s_row[Dd];
  const int bi = blockIdx.x, d = threadIdx.x;
  const int b = bi >> 8, i = bi & 255;
  s_row[d] = node_s[(size_t)bi*Dd + d];
  __syncthreads();
  float acc = 0.f;
  #pragma unroll 8
  for (int k=0;k<Dd;k++) acc += s_row[k]*src_w[k*Dd + d];
  hT_out[((size_t)b*Dd + d)*Nn + i] = acc;   // transposed: [d][j]
}

// ---- kernel 2: all-MFMA pipeline, one block per (b,i) ----------------------
// Wave w owns d-cols [w*32, w*32+32). GEMM1 (swapped: A=w1^T, B=rbf^T) ->
// SiLU -> s_hid[j][hid] (b64 packed stores) -> GEMM2 -> G -> reduction MFMA.
__global__ __launch_bounds__(256,3) void se3_mfma4(
    const float* __restrict__ node_v,
    const float* __restrict__ rbf,
    const float* __restrict__ r_hat,
    const float* __restrict__ maskp,
    const float* __restrict__ r0w1, const float* __restrict__ r0b1,
    const float* __restrict__ r0w2, const float* __restrict__ r0b2,
    const float* __restrict__ r1w1, const float* __restrict__ r1b1,
    const float* __restrict__ r1w2, const float* __restrict__ r1b2,
    const float* __restrict__ r2w1, const float* __restrict__ r2b1,
    const float* __restrict__ r2w2, const float* __restrict__ r2b2,
    const float* __restrict__ r3w1, const float* __restrict__ r3b1,
    const float* __restrict__ r3w2, const float* __restrict__ r3b2,
    const float* __restrict__ ln_g, const float* __restrict__ ln_b,
    const float* __restrict__ out_w, const float* __restrict__ out_b,
    const float* __restrict__ v_scale, const float* __restrict__ t_scale,
    const float* __restrict__ hT,
    float* __restrict__ out_s, float* __restrict__ out_v, float* __restrict__ out_t)
{
  // LDS total = 44,760 B  -> 3 blocks/CU
  __shared__ u16   s_hid[64*136];      // 17408: hidden for 64-j chunk, [j][hid]
  __shared__ u16   s_YT[10*264];       //  5280: rows 0=mask,1-3=Y1*m,4-8=Y2*m,9=mask
  __shared__ u16   s_Y1r[3*264];       //  1584: raw Y1 (for dot MFMA A)
  __shared__ u16   s_G[4*32*72];       // 18432: per-wave G_T[d][j]
  __shared__ float s_msg[Dd];          //   512
  __shared__ float s_xn[Dd];           //   512
  __shared__ float s_part[2*Dd];       //  1024
  __shared__ float s_mv[2];            //     8

  const int tid  = threadIdx.x;
  const int bi   = blockIdx.x;            // b*N + i
  const int b    = bi >> 8;
  const int lane = tid & 63;
  const int w    = tid >> 6;              // wave 0..3
  const int q    = lane >> 4;             // quad
  const int cc   = lane & 15;
  const int dbase= w*32;                  // this wave's d-col base

  // ---- setup: stacked-Y rows (mask folded), raw Y1 ----
  {
    int j = tid;
    size_t pidx = (size_t)bi*Nn + j;
    float mk = maskp[pidx];
    float x = r_hat[pidx*3+0];
    float y = r_hat[pidx*3+1];
    float z = r_hat[pidx*3+2];
    const float SQ3=1.7320508075688772f;   // sqrt(3)
    const float C15=3.8729833462074170f;   // sqrt(15)
    const float C5H=1.1180339887498949f;   // 0.5*sqrt(5)
    float y1a=SQ3*x, y1b=SQ3*y, y1c=SQ3*z;
    s_YT[0*264+j]=f2bf(mk);
    s_YT[1*264+j]=f2bf(y1a*mk);
    s_YT[2*264+j]=f2bf(y1b*mk);
    s_YT[3*264+j]=f2bf(y1c*mk);
    s_YT[4*264+j]=f2bf(C15*x*y*mk);
    s_YT[5*264+j]=f2bf(C15*y*z*mk);
    s_YT[6*264+j]=f2bf(C5H*(3.f*z*z-1.f)*mk);
    s_YT[7*264+j]=f2bf(C15*x*z*mk);
    s_YT[8*264+j]=f2bf(0.5f*C15*(x*x-y*y)*mk);
    s_YT[9*264+j]=f2bf(mk);
    s_Y1r[0*264+j]=f2bf(y1a);
    s_Y1r[1*264+j]=f2bf(y1b);
    s_Y1r[2*264+j]=f2bf(y1c);
  }

  const float* rbf_blk = rbf + (size_t)bi*Nn*Rr;

  // ---- node_v B-fragments for the dot MFMA: B[k=c][n=d], k<3 on quad 0 ----
  bf16x8 vBf[2];
  {
    const float* nv = node_v + (size_t)bi*3*Dd;
    #pragma unroll
    for (int nt=0;nt<2;nt++){
      int dd = dbase+nt*16+cc;
      bf16x8 t = {0,0,0,0,0,0,0,0};
      if (q==0){
        t[0]=f2bfs(nv[0*Dd+dd]);
        t[1]=f2bfs(nv[1*Dd+dd]);
        t[2]=f2bfs(nv[2*Dd+dd]);
      }
      vBf[nt]=t;
    }
  }

  const f32x4 zf = {0.f,0.f,0.f,0.f};
  f32x4 accred[2] = {zf, zf};           // rows 0..9 = the 10 reduced outputs

  #pragma unroll 1
  for (int p=0;p<4;p++){
    const float* W1p = (p==0)?r0w1:(p==1)?r1w1:(p==2)?r2w1:r3w1;
    const float* B1p = (p==0)?r0b1:(p==1)?r1b1:(p==2)?r2b1:r3b1;
    const float* W2p = (p==0)?r0w2:(p==1)?r1w2:(p==2)?r2w2:r3w2;
    const float* B2p = (p==0)?r0b2:(p==1)?r1b2:(p==2)?r2b2:r3b2;
    const int lo = (p==0)?0:(p==1)?1:(p==2)?4:9;
    const int hi = (p==0)?0:(p==1)?3:(p==2)?8:9;
    const u32 gmask = (cc>=lo && cc<=hi) ? 0xFFFFFFFFu : 0u;
    const u16* ytrow = &s_YT[(cc<10?cc:9)*264];

    // per-p fragments: w1f (A of GEMM1) 8 VGPR, w2f (B of GEMM2) 32 VGPR
    bf16x8 w1f[2];
    bf16x8 w2f[2][4];
    f32x4  b1q[2];                     // bias1[hid = dbase+mt*16+q*4+r]
    float  b2v[2];
    #pragma unroll
    for (int mt=0;mt<2;mt++){
      int dd = dbase+mt*16+cc;
      b1q[mt] = *(const f32x4*)(B1p + dbase + mt*16 + q*4);
      b2v[mt] = B2p[dd];
      #pragma unroll
      for (int jj=0;jj<8;jj++)
        w1f[mt][jj] = f2bfs(W1p[(q*8+jj)*Dd + dd]);
      #pragma unroll
      for (int ks=0;ks<4;ks++){
        #pragma unroll
        for (int jj=0;jj<8;jj++)
          w2f[mt][ks][jj] = f2bfs(W2p[(ks*32+q*8+jj)*Dd + dd]);
      }
    }

    #pragma unroll 1
    for (int ch=0; ch<4; ch++){          // 4 chunks of 64 j
      __syncthreads();                   // s_hid free (all waves' GEMM2 done)
      // ---- GEMM1 (swapped): C1[hid, j] = w1^T @ rbf^T; SiLU; b64 store ----
      #pragma unroll
      for (int jt=0;jt<4;jt++){
        const float* rp = rbf_blk + (size_t)(ch*64 + jt*16 + cc)*Rr + q*8;
        f32x4 ra0 = *(const f32x4*)rp;
        f32x4 ra1 = *(const f32x4*)(rp+4);
        bf16x8 raf = {f2bfs(ra0[0]),f2bfs(ra0[1]),f2bfs(ra0[2]),f2bfs(ra0[3]),
                      f2bfs(ra1[0]),f2bfs(ra1[1]),f2bfs(ra1[2]),f2bfs(ra1[3])};
        #pragma unroll
        for (int mt=0;mt<2;mt++){
          f32x4 hc = __builtin_amdgcn_mfma_f32_16x16x32_bf16(w1f[mt], raf, zf, 0,0,0);
          u16 g4[4];
          #pragma unroll
          for (int r=0;r<4;r++){
            float x  = hc[r] + b1q[mt][r];
            float e  = __expf(-x);
            g4[r] = f2bf(x*__builtin_amdgcn_rcpf(1.f+e));
          }
          u32x2 pk = { (u32)g4[0] | ((u32)g4[1]<<16),
                       (u32)g4[2] | ((u32)g4[3]<<16) };
          // C1: lane cc = j col, rows hid = q*4+r  ->  s_hid[j][hid]
          *(u32x2*)&s_hid[(jt*16+cc)*136 + dbase + mt*16 + q*4] = pk;
        }
      }
      __syncthreads();                   // hidden ready
      // ---- GEMM2: hidden @ w2 -> G = rad*h (p<3) or rad*dot (p3) ----
      #pragma unroll
      for (int m=0;m<4;m++){
        bf16x8 af[4];
        #pragma unroll
        for (int ks=0;ks<4;ks++)
          af[ks] = *(const bf16x8*)&s_hid[(m*16+cc)*136 + ks*32 + q*8];

        f32x4 dotC[2];
        if (p==3){                       // dot(v, Y1) via K=3 MFMA
          bf16x8 aY = {0,0,0,0,0,0,0,0};
          if (q==0){
            int j = ch*64 + m*16 + cc;
            aY[0]=(short)s_Y1r[0*264+j];
            aY[1]=(short)s_Y1r[1*264+j];
            aY[2]=(short)s_Y1r[2*264+j];
          }
          #pragma unroll
          for (int nt=0;nt<2;nt++)
            dotC[nt] = __builtin_amdgcn_mfma_f32_16x16x32_bf16(aY, vBf[nt], zf, 0,0,0);
        }

        #pragma unroll
        for (int nt=0;nt<2;nt++){
          f32x4 c2 = zf;
          #pragma unroll
          for (int ks=0;ks<4;ks++)
            c2 = __builtin_amdgcn_mfma_f32_16x16x32_bf16(af[ks], w2f[nt][ks], c2, 0,0,0);
          int dd = dbase+nt*16+cc;
          u16 g4[4];
          if (p<3){
            f32x4 h4 = *(const f32x4*)(hT + ((size_t)(b*Dd) + dd)*Nn + ch*64 + m*16 + q*4);
            #pragma unroll
            for (int r=0;r<4;r++)
              g4[r] = f2bf((c2[r]+b2v[nt]) * h4[r]);
          } else {
            #pragma unroll
            for (int r=0;r<4;r++)
              g4[r] = f2bf((c2[r]+b2v[nt]) * dotC[nt][r]);
          }
          u32x2 pk = { (u32)g4[0] | ((u32)g4[1]<<16),
                       (u32)g4[2] | ((u32)g4[3]<<16) };
          *(u32x2*)&s_G[(w*32 + nt*16 + cc)*72 + m*16 + q*4] = pk;
        }
      }
      // ---- j-reduction MFMA (intra-wave: no barrier needed) ----
      #pragma unroll
      for (int ks2=0;ks2<2;ks2++){
        bf16x8 aR = *(const bf16x8*)(ytrow + ch*64 + ks2*32 + q*8);
        u32* arp = (u32*)&aR;
        arp[0]&=gmask; arp[1]&=gmask; arp[2]&=gmask; arp[3]&=gmask;
        #pragma unroll
        for (int nt=0;nt<2;nt++){
          bf16x8 bG = *(const bf16x8*)&s_G[(w*32 + nt*16 + cc)*72 + ks2*32 + q*8];
          accred[nt] = __builtin_amdgcn_mfma_f32_16x16x32_bf16(aR, bG, accred[nt], 0,0,0);
        }
      }
    }
  }

  // ---- scatter accred rows -> outputs / LN inputs ----
  #pragma unroll
  for (int nt=0;nt<2;nt++){
    int d = dbase + nt*16 + cc;
    #pragma unroll
    for (int r=0;r<4;r++){
      int rw = q*4 + r;
      float val = accred[nt][r];
      if (rw==0)      s_msg[d] = val;
      else if (rw<=3) out_v[(size_t)bi*3*Dd + (size_t)(rw-1)*Dd + d] = val*v_scale[d];
      else if (rw<=8) out_t[(size_t)bi*5*Dd + (size_t)(rw-4)*Dd + d] = val*t_scale[d];
      else if (rw==9) s_xn[d] = val;
    }
  }
  __syncthreads();

  // ---- LayerNorm stats (wave 0), biased var, guarded ----
  if (tid < 64){
    float a0=s_msg[tid]+s_xn[tid], a1=s_msg[tid+64]+s_xn[tid+64];
    float s1=a0+a1, s2=a0*a0+a1*a1;
    #pragma unroll
    for (int off=1;off<64;off<<=1){
      s1 += __shfl_xor(s1,off);
      s2 += __shfl_xor(s2,off);
    }
    if (tid==0){
      float m   = s1*(1.f/Dd);
      float var = fmaxf(s2*(1.f/Dd) - m*m, 0.f);
      s_mv[0]=m;
      s_mv[1]=rsqrtf(var+1e-5f);
    }
  }
  __syncthreads();
  if (tid < Dd){
    float msg = s_msg[tid]+s_xn[tid];
    s_xn[tid] = (msg - s_mv[0])*s_mv[1]*ln_g[tid] + ln_b[tid];
  }
  __syncthreads();

  // ---- delta_s = xn @ out_w + out_b ----
  {
    int dp = tid & 127, seg = tid >> 7;
    float pa = 0.f;
    #pragma unroll 8
    for (int k=seg*64;k<seg*64+64;k++)
      pa += s_xn[k]*out_w[k*Dd+dp];
    s_part[seg*Dd+dp]=pa;
  }
  __syncthreads();
  if (tid < Dd)
    out_s[(size_t)bi*Dd+tid] = s_part[tid]+s_part[Dd+tid]+out_b[tid];
}

extern "C" void kernel_launch(void* const* d_in, const int* in_sizes, int n_in,
                              void* d_out, int out_size, void* d_ws, size_t ws_size,
                              hipStream_t stream) {
  const float* node_s = (const float*)d_in[0];
  const float* node_v = (const float*)d_in[1];
  // d_in[2] = node_t (unused by reference)
  const float* rbf    = (const float*)d_in[3];
  const float* r_hat  = (const float*)d_in[4];
  const float* maskp  = (const float*)d_in[5];
  const float* r0w1=(const float*)d_in[6],  *r0b1=(const float*)d_in[7];
  const float* r0w2=(const float*)d_in[8],  *r0b2=(const float*)d_in[9];
  const float* r1w1=(const float*)d_in[10], *r1b1=(const float*)d_in[11];
  const float* r1w2=(const float*)d_in[12], *r1b2=(const float*)d_in[13];
  const float* r2w1=(const float*)d_in[14], *r2b1=(const float*)d_in[15];
  const float* r2w2=(const float*)d_in[16], *r2b2=(const float*)d_in[17];
  const float* r3w1=(const float*)d_in[18], *r3b1=(const float*)d_in[19];
  const float* r3w2=(const float*)d_in[20], *r3b2=(const float*)d_in[21];
  const float* src_w  =(const float*)d_in[22];
  const float* ln_g   =(const float*)d_in[23];
  const float* ln_b   =(const float*)d_in[24];
  const float* out_w  =(const float*)d_in[25];
  const float* out_b  =(const float*)d_in[26];
  const float* v_scale=(const float*)d_in[27];
  const float* t_scale=(const float*)d_in[28];

  float* hT = (float*)d_ws;                      // h transposed [b][d][j], 256 KiB
  float* out_s = (float*)d_out;
  float* out_v = out_s + (size_t)Bb*Nn*Dd;
  float* out_t = out_v + (size_t)Bb*Nn*3*Dd;

  hproj_kernel<<<dim3(Bb*Nn), dim3(Dd), 0, stream>>>(node_s, src_w, hT);
  se3_mfma4<<<dim3(Bb*Nn), dim3(256), 0, stream>>>(
      node_v, rbf, r_hat, maskp,
      r0w1,r0b1,r0w2,r0b2, r1w1,r1b1,r1w2,r1b2,
      r2w1,r2b1,r2w2,r2b2, r3w1,r3b1,r3w2,r3b2,
      ln_g, ln_b, out_w, out_b, v_scale, t_scale,
      hT, out_s, out_v, out_t);
}